// Round 18
// baseline (409.109 us; speedup 1.0000x reference)
//
#include <hip/hip_runtime.h>

#define B_ 256
#define T_ 500
#define N_ 256
#define BN_ 65536            // B_*N_
#define STP_ 196608          // 3*B_*N_ (states per-t stride)
#define TW 64                // t-window per chunk
#define NCHUNK 8             // ceil(500/64)

// Soft barrier: LDS-visibility sync without vmcnt(0) store drain (stores have
// no in-kernel consumer). sched_barrier fences per rule #18.
#define SOFT_BAR() do {                                   \
    __builtin_amdgcn_sched_barrier(0);                    \
    asm volatile("s_waitcnt lgkmcnt(0)" ::: "memory");    \
    __builtin_amdgcn_s_barrier();                         \
    __builtin_amdgcn_sched_barrier(0);                    \
} while (0)

// ---------------------------------------------------------------------------
// Fused GEMM + Izhikevich scan, chunk-PIPELINED (R17, 362 us) + ONE change:
// the two dense B-fragment ds_read_b128 per kk are replaced by ONE b128
// (lane L reads cols 4L..4L+3 of W-row kk) + 4x v_permlane32_swap_b32.
// swap(b0,b1) with b0=b1=loaded value gives b0 = lane(L&31)'s value
// (= old Wc[kk*256+h4]) and b1 = lane((L&31)+32)'s value (= old ..+128):
// bit-identical operands into the unchanged FMA chain, but 25% fewer LDS
// instructions in G (4 -> 3 per kk; permlane is VALU-pipe, which has slack).
// Discriminates LDS-pipe-bound (model a: -40 us) vs FMA-bound (null).
// Scan text = R14-PINNED fmaf form. I bit-identical.
// ---------------------------------------------------------------------------
__global__ __launch_bounds__(256)
void fused_snn_kernel(const float* __restrict__ X, const float* __restrict__ W1,
                      float* __restrict__ out_s, float* __restrict__ states,
                      float* __restrict__ out_dec,
                      const float* __restrict__ st_snn, const float* __restrict__ st_li,
                      const float* __restrict__ W2,
                      const float* __restrict__ pa, const float* __restrict__ pb,
                      const float* __restrict__ pc, const float* __restrict__ pd,
                      const float* __restrict__ pv0, const float* __restrict__ pv1,
                      const float* __restrict__ pv2, const float* __restrict__ ptau,
                      const float* __restrict__ pth, const float* __restrict__ pleak) {
    __shared__ float Xl[TW * 256];              // 64 KB: X chunk c, [k][t]
    __shared__ float Il[TW * 256];              // 64 KB: I chunk c-1, [t][n]
    __shared__ float Ws[2][8 * 256];            // 16 KB: W1t BK=8 slice dbuf
    __shared__ unsigned long long dotm[T_][4];  // 16000 B: per-wave spike masks

    const int bb   = blockIdx.x;
    const int tid  = threadIdx.x;
    const int w    = tid >> 6;
    const int lane = tid & 63;
    const int boff = bb * 256 + tid;

    // scan per-thread state & params
    float v = st_snn[boff];
    float u = st_snn[BN_ + boff];
    const float a_   = pa[tid];
    const float b_   = pb[tid];
    const float c_   = pc[tid];
    const float d_   = pd[tid];
    const float v0_  = pv0[tid];
    const float v1_  = pv1[tid];
    const float v2_  = pv2[tid];
    const float coef = (1.0f / ptau[tid]) * a_;  // (DT/tau_u)*a, DT=1
    const float th_  = pth[tid];

    // GEMM microtile: 8 t-groups x 32 n-groups, 8x8 per thread
    const int g   = tid >> 5;            // t rows 8g..8g+7
    const int tg  = g << 3;
    const int h4  = (tid & 31) << 2;     // n cols h4..h4+3 and h4+128..h4+131
    const int l4  = lane << 2;           // B-row quarter this lane loads

    const float* Xb = X + (size_t)bb * (T_ * 256);
    const int tl = tid & 63;             // X-stage t_loc
    const int wq = (tid >> 6) << 2;      // X-stage k sub-quad

    // W slice 0 (k 0..7) held permanently in regs (chunk-invariant)
    const float* Wr0 = W1 + (size_t)tid * 256;
    const float4 z0 = *(const float4*)(Wr0 + 0);
    const float4 z1 = *(const float4*)(Wr0 + 4);

    // stage X chunk 0 (valid=64) and W slice 0
    float4 ra[16];
    {
        const float* Xrow = Xb + (size_t)tl * 256;
#pragma unroll
        for (int r = 0; r < 16; ++r)
            ra[r] = *(const float4*)(Xrow + r * 16 + wq);
    }
#pragma unroll
    for (int r = 0; r < 16; ++r) {
        const int k = r * 16 + wq;
        Xl[(k + 0) * 64 + tl] = ra[r].x;
        Xl[(k + 1) * 64 + tl] = ra[r].y;
        Xl[(k + 2) * 64 + tl] = ra[r].z;
        Xl[(k + 3) * 64 + tl] = ra[r].w;
    }
    {
        float* Wd = &Ws[0][0];
        Wd[0*256+tid]=z0.x; Wd[1*256+tid]=z0.y; Wd[2*256+tid]=z0.z; Wd[3*256+tid]=z0.w;
        Wd[4*256+tid]=z1.x; Wd[5*256+tid]=z1.y; Wd[6*256+tid]=z1.z; Wd[7*256+tid]=z1.w;
    }
    SOFT_BAR();

    float Inx = 0.f;                     // scan I-prefetch register

    for (int cc = 0; cc < NCHUNK; ++cc) {
        const int tb = (cc - 1) * TW;    // scan chunk base (used when cc>0)

        float acc[8][8];
#pragma unroll
        for (int i = 0; i < 8; ++i)
#pragma unroll
            for (int j = 0; j < 8; ++j) acc[i][j] = 0.f;

        for (int ks = 0; ks < 32; ++ks) {
            float4 q0, q1;
            if (ks < 31) {               // next W slice (k 8(ks+1)..+8) from L2
                const float* Wr = W1 + (size_t)tid * 256 + (ks + 1) * 8;
                q0 = *(const float4*)(Wr);
                q1 = *(const float4*)(Wr + 4);
            }
            if (ks == 24 && cc + 1 < NCHUNK) {   // issue next-chunk X loads
                const int t0n    = (cc + 1) * TW;
                const int validn = (T_ - t0n < TW) ? (T_ - t0n) : TW;
                const int tsrc   = t0n + ((tl < validn) ? tl : (validn - 1));
                const float* Xrow = Xb + (size_t)tsrc * 256;
#pragma unroll
                for (int r = 0; r < 16; ++r)
                    ra[r] = *(const float4*)(Xrow + r * 16 + wq);
            }
            const float* Wc = &Ws[ks & 1][0];
            const int kbase = ks << 3;
#pragma unroll
            for (int kk = 0; kk < 8; ++kk) {
                const float4 a0 = *(const float4*)&Xl[(kbase + kk) * 64 + tg];
                const float4 a1 = *(const float4*)&Xl[(kbase + kk) * 64 + tg + 4];
                // ONE dense b128: lane L holds cols 4L..4L+3 of W-row kk
                const float4 qw = *(const float4*)&Wc[kk * 256 + l4];
                // b0 = lane(L&31)'s qw (= cols h4..h4+3)
                // b1 = lane((L&31)+32)'s qw (= cols h4+128..h4+131)
                float4 b0 = qw, b1 = qw;
                asm("v_permlane32_swap_b32 %0, %1" : "+v"(b0.x), "+v"(b1.x));
                asm("v_permlane32_swap_b32 %0, %1" : "+v"(b0.y), "+v"(b1.y));
                asm("v_permlane32_swap_b32 %0, %1" : "+v"(b0.z), "+v"(b1.z));
                asm("v_permlane32_swap_b32 %0, %1" : "+v"(b0.w), "+v"(b1.w));
                const float avr[8] = {a0.x, a0.y, a0.z, a0.w, a1.x, a1.y, a1.z, a1.w};
                const float bvr[8] = {b0.x, b0.y, b0.z, b0.w, b1.x, b1.y, b1.z, b1.w};
#pragma unroll
                for (int i = 0; i < 8; ++i)
#pragma unroll
                    for (int j = 0; j < 8; ++j)
                        acc[i][j] += avr[i] * bvr[j];
            }
            // interleaved scan: 2 steps of chunk cc-1 (stores drain under GEMM)
            if (cc > 0) {
#pragma unroll
                for (int e = 0; e < 2; ++e) {
                    const int q = (ks << 1) + e;
                    const float Icur = Inx;
                    if (q + 1 < TW) Inx = Il[(q + 1) * 256 + tid];
                    const int t = tb + q;
                    const size_t pbase = (size_t)t * STP_ + boff;

                    // canonical explicit-fma form (pinned, R14 verbatim):
                    const float m1 = v2_ * v;
                    const float t2 = v1_ * v;
                    const float P  = __builtin_fmaf(m1, v, t2);
                    const float Q  = (P + v0_) - u;
                    const float vm = v + (Q + Icur);
                    const float tb2 = __builtin_fmaf(b_, v, -u);
                    const float um = __builtin_fmaf(coef, tb2, u);

                    const bool  sp = (vm - th_) > 0.f;
                    const float s  = sp ? 1.f : 0.f;
                    v = sp ? c_ : vm;        // == vm*(1-s)+s*c exactly
                    u = sp ? (um + d_) : um; // == um + s*d

                    states[pbase]           = v;
                    states[pbase + BN_]     = u;
                    states[pbase + 2 * BN_] = s;
                    out_s[(size_t)t * BN_ + boff] = s;

                    const unsigned long long mset = __ballot(sp);
                    if (lane == 0) dotm[t][w] = mset;
                }
            }
            if (ks < 31) {               // write next W slice after FMAs
                float* Wd = &Ws[(ks + 1) & 1][0];
                Wd[0*256+tid]=q0.x; Wd[1*256+tid]=q0.y; Wd[2*256+tid]=q0.z; Wd[3*256+tid]=q0.w;
                Wd[4*256+tid]=q1.x; Wd[5*256+tid]=q1.y; Wd[6*256+tid]=q1.z; Wd[7*256+tid]=q1.w;
            }
            SOFT_BAR();
        }

        // chunk end: acc -> Il (scan of cc-1 fully consumed Il; barrier above)
#pragma unroll
        for (int i = 0; i < 8; ++i) {
            const int t = tg + i;
            *(float4*)&Il[t * 256 + h4] =
                make_float4(acc[i][0], acc[i][1], acc[i][2], acc[i][3]);
            *(float4*)&Il[t * 256 + h4 + 128] =
                make_float4(acc[i][4], acc[i][5], acc[i][6], acc[i][7]);
        }
        if (cc + 1 < NCHUNK) {           // next chunk's X (regs, issued ks=24)
#pragma unroll
            for (int r = 0; r < 16; ++r) {
                const int k = r * 16 + wq;
                Xl[(k + 0) * 64 + tl] = ra[r].x;
                Xl[(k + 1) * 64 + tl] = ra[r].y;
                Xl[(k + 2) * 64 + tl] = ra[r].z;
                Xl[(k + 3) * 64 + tl] = ra[r].w;
            }
            float* Wd = &Ws[0][0];       // restage W slice 0 from held regs
            Wd[0*256+tid]=z0.x; Wd[1*256+tid]=z0.y; Wd[2*256+tid]=z0.z; Wd[3*256+tid]=z0.w;
            Wd[4*256+tid]=z1.x; Wd[5*256+tid]=z1.y; Wd[6*256+tid]=z1.z; Wd[7*256+tid]=z1.w;
        }
        SOFT_BAR();
        Inx = Il[tid];                   // prefetch first I of chunk cc's scan
    }

    // epilogue: scan chunk 7 (52 steps), not overlapped
    {
        const int tbE = 7 * TW;          // 448
        for (int q = 0; q < 52; ++q) {
            const float Icur = Inx;
            if (q + 1 < 52) Inx = Il[(q + 1) * 256 + tid];
            const int t = tbE + q;
            const size_t pbase = (size_t)t * STP_ + boff;

            const float m1 = v2_ * v;
            const float t2 = v1_ * v;
            const float P  = __builtin_fmaf(m1, v, t2);
            const float Q  = (P + v0_) - u;
            const float vm = v + (Q + Icur);
            const float tb2 = __builtin_fmaf(b_, v, -u);
            const float um = __builtin_fmaf(coef, tb2, u);

            const bool  sp = (vm - th_) > 0.f;
            const float s  = sp ? 1.f : 0.f;
            v = sp ? c_ : vm;
            u = sp ? (um + d_) : um;

            states[pbase]           = v;
            states[pbase + BN_]     = u;
            states[pbase + 2 * BN_] = s;
            out_s[(size_t)t * BN_ + boff] = s;

            const unsigned long long mset = __ballot(sp);
            if (lane == 0) dotm[t][w] = mset;
        }
    }
    __syncthreads();                     // dotm complete

    // masks -> dots (w2l/dotf overlay on dead Ws region: 256+2000 <= 4096 floats)
    float* scr  = &Ws[0][0];
    float* w2l  = scr;                   // [256]
    float* dotf = scr + 256;             // [500][4]
    w2l[tid] = W2[tid];
    __syncthreads();
    for (int p = tid; p < T_ * 4; p += 256) {
        const int t  = p >> 2;
        const int ww = p & 3;
        unsigned long long m = dotm[t][ww];
        const float* wl = &w2l[ww << 6];
        float sum = 0.f;
        while (m) {
            const int i = __builtin_ctzll(m);
            sum += wl[i];
            m &= (m - 1);
        }
        dotf[t * 4 + ww] = sum;
    }
    __syncthreads();

    if (tid == 0) {
        const float lk_  = pleak[0];
        const float olk_ = 1.0f - lk_;
        float li = st_li[bb];
        for (int t = 0; t < T_; ++t) {
            const float dot = (dotf[t*4+0] + dotf[t*4+1]) + (dotf[t*4+2] + dotf[t*4+3]);
            li = lk_ * li + olk_ * dot;
            out_dec[(size_t)t * 256 + bb] = li;
        }
    }
}

// ---------------------------------------------------------------------------
extern "C" void kernel_launch(void* const* d_in, const int* in_sizes, int n_in,
                              void* d_out, int out_size, void* d_ws, size_t ws_size,
                              hipStream_t stream) {
    const float* input  = (const float*)d_in[0];   // [B,T,N]
    const float* st_snn = (const float*)d_in[1];   // [3,B,N]
    const float* st_li  = (const float*)d_in[2];   // [B,1]
    const float* W1     = (const float*)d_in[3];   // [N,N]
    const float* W2     = (const float*)d_in[4];   // [1,N]
    const float* pa     = (const float*)d_in[5];
    const float* pb     = (const float*)d_in[6];
    const float* pc     = (const float*)d_in[7];
    const float* pd     = (const float*)d_in[8];
    const float* pv0    = (const float*)d_in[9];
    const float* pv1    = (const float*)d_in[10];
    const float* pv2    = (const float*)d_in[11];
    const float* ptau   = (const float*)d_in[12];
    const float* pth    = (const float*)d_in[13];
    const float* pleak  = (const float*)d_in[14];

    float* out        = (float*)d_out;
    float* out_s      = out;                                        // [500,256,256]
    float* out_states = out + (size_t)T_ * BN_;                     // [500,3,256,256]
    float* out_dec    = out + (size_t)T_ * BN_ + (size_t)T_ * STP_; // [500,256]

    fused_snn_kernel<<<dim3(B_), dim3(256), 0, stream>>>(
        input, W1, out_s, out_states, out_dec, st_snn, st_li, W2,
        pa, pb, pc, pd, pv0, pv1, pv2, ptau, pth, pleak);
}

// Round 19
// 389.296 us; speedup vs baseline: 1.0509x; 1.0509x over previous
//
#include <hip/hip_runtime.h>

#define B_ 256
#define T_ 500
#define N_ 256
#define BN_ 65536            // B_*N_
#define STP_ 196608          // 3*B_*N_ (states per-t stride)
#define TW 64                // t-window per chunk
#define NCHUNK 8             // ceil(500/64)

// Soft barrier: LDS-visibility sync without vmcnt(0) store drain (stores have
// no in-kernel consumer). sched_barrier fences per rule #18.
#define SOFT_BAR() do {                                   \
    __builtin_amdgcn_sched_barrier(0);                    \
    asm volatile("s_waitcnt lgkmcnt(0)" ::: "memory");    \
    __builtin_amdgcn_s_barrier();                         \
    __builtin_amdgcn_sched_barrier(0);                    \
} while (0)

// ---------------------------------------------------------------------------
// Fused GEMM + Izhikevich scan, chunk-PIPELINED (R17 base, permlane REVERTED:
// R18 showed dependent VALU between LDS load and FMA costs 2.4x its issue).
// ONE change vs R17: the two s-stores per scan step (states s-plane, out_s)
// are moved to an end-pass that materializes them from the ballot masks in
// dotm (s == mask bit, bit-identical). The interleaved loop keeps only the
// v,u stores -> less vm-issue/backpressure on the critical path; the end-pass
// is pure streaming (independent iterations, write-BW-bound ~42 us).
// Scan v/u text = R14-PINNED fmaf form. I bit-identical.
// ---------------------------------------------------------------------------
__global__ __launch_bounds__(256)
void fused_snn_kernel(const float* __restrict__ X, const float* __restrict__ W1,
                      float* __restrict__ out_s, float* __restrict__ states,
                      float* __restrict__ out_dec,
                      const float* __restrict__ st_snn, const float* __restrict__ st_li,
                      const float* __restrict__ W2,
                      const float* __restrict__ pa, const float* __restrict__ pb,
                      const float* __restrict__ pc, const float* __restrict__ pd,
                      const float* __restrict__ pv0, const float* __restrict__ pv1,
                      const float* __restrict__ pv2, const float* __restrict__ ptau,
                      const float* __restrict__ pth, const float* __restrict__ pleak) {
    __shared__ float Xl[TW * 256];              // 64 KB: X chunk c, [k][t]
    __shared__ float Il[TW * 256];              // 64 KB: I chunk c-1, [t][n]
    __shared__ float Ws[2][8 * 256];            // 16 KB: W1t BK=8 slice dbuf
    __shared__ unsigned long long dotm[T_][4];  // 16000 B: per-wave spike masks

    const int bb   = blockIdx.x;
    const int tid  = threadIdx.x;
    const int w    = tid >> 6;
    const int lane = tid & 63;
    const int boff = bb * 256 + tid;

    // scan per-thread state & params
    float v = st_snn[boff];
    float u = st_snn[BN_ + boff];
    const float a_   = pa[tid];
    const float b_   = pb[tid];
    const float c_   = pc[tid];
    const float d_   = pd[tid];
    const float v0_  = pv0[tid];
    const float v1_  = pv1[tid];
    const float v2_  = pv2[tid];
    const float coef = (1.0f / ptau[tid]) * a_;  // (DT/tau_u)*a, DT=1
    const float th_  = pth[tid];

    // GEMM microtile: 8 t-groups x 32 n-groups, 8x8 per thread
    const int g   = tid >> 5;            // t rows 8g..8g+7
    const int tg  = g << 3;
    const int h4  = (tid & 31) << 2;     // n cols h4..h4+3 and h4+128..h4+131

    const float* Xb = X + (size_t)bb * (T_ * 256);
    const int tl = tid & 63;             // X-stage t_loc
    const int wq = (tid >> 6) << 2;      // X-stage k sub-quad

    // W slice 0 (k 0..7) held permanently in regs (chunk-invariant)
    const float* Wr0 = W1 + (size_t)tid * 256;
    const float4 z0 = *(const float4*)(Wr0 + 0);
    const float4 z1 = *(const float4*)(Wr0 + 4);

    // stage X chunk 0 (valid=64) and W slice 0
    float4 ra[16];
    {
        const float* Xrow = Xb + (size_t)tl * 256;
#pragma unroll
        for (int r = 0; r < 16; ++r)
            ra[r] = *(const float4*)(Xrow + r * 16 + wq);
    }
#pragma unroll
    for (int r = 0; r < 16; ++r) {
        const int k = r * 16 + wq;
        Xl[(k + 0) * 64 + tl] = ra[r].x;
        Xl[(k + 1) * 64 + tl] = ra[r].y;
        Xl[(k + 2) * 64 + tl] = ra[r].z;
        Xl[(k + 3) * 64 + tl] = ra[r].w;
    }
    {
        float* Wd = &Ws[0][0];
        Wd[0*256+tid]=z0.x; Wd[1*256+tid]=z0.y; Wd[2*256+tid]=z0.z; Wd[3*256+tid]=z0.w;
        Wd[4*256+tid]=z1.x; Wd[5*256+tid]=z1.y; Wd[6*256+tid]=z1.z; Wd[7*256+tid]=z1.w;
    }
    SOFT_BAR();

    float Inx = 0.f;                     // scan I-prefetch register

    for (int cc = 0; cc < NCHUNK; ++cc) {
        const int tb = (cc - 1) * TW;    // scan chunk base (used when cc>0)

        float acc[8][8];
#pragma unroll
        for (int i = 0; i < 8; ++i)
#pragma unroll
            for (int j = 0; j < 8; ++j) acc[i][j] = 0.f;

        for (int ks = 0; ks < 32; ++ks) {
            float4 q0, q1;
            if (ks < 31) {               // next W slice (k 8(ks+1)..+8) from L2
                const float* Wr = W1 + (size_t)tid * 256 + (ks + 1) * 8;
                q0 = *(const float4*)(Wr);
                q1 = *(const float4*)(Wr + 4);
            }
            if (ks == 24 && cc + 1 < NCHUNK) {   // issue next-chunk X loads
                const int t0n    = (cc + 1) * TW;
                const int validn = (T_ - t0n < TW) ? (T_ - t0n) : TW;
                const int tsrc   = t0n + ((tl < validn) ? tl : (validn - 1));
                const float* Xrow = Xb + (size_t)tsrc * 256;
#pragma unroll
                for (int r = 0; r < 16; ++r)
                    ra[r] = *(const float4*)(Xrow + r * 16 + wq);
            }
            const float* Wc = &Ws[ks & 1][0];
            const int kbase = ks << 3;
#pragma unroll
            for (int kk = 0; kk < 8; ++kk) {
                const float4 a0 = *(const float4*)&Xl[(kbase + kk) * 64 + tg];
                const float4 a1 = *(const float4*)&Xl[(kbase + kk) * 64 + tg + 4];
                const float4 b0 = *(const float4*)&Wc[kk * 256 + h4];
                const float4 b1 = *(const float4*)&Wc[kk * 256 + h4 + 128];
                const float avr[8] = {a0.x, a0.y, a0.z, a0.w, a1.x, a1.y, a1.z, a1.w};
                const float bvr[8] = {b0.x, b0.y, b0.z, b0.w, b1.x, b1.y, b1.z, b1.w};
#pragma unroll
                for (int i = 0; i < 8; ++i)
#pragma unroll
                    for (int j = 0; j < 8; ++j)
                        acc[i][j] += avr[i] * bvr[j];
            }
            // interleaved scan: 2 steps of chunk cc-1 (v,u stores only;
            // s materialized from dotm in the end-pass)
            if (cc > 0) {
#pragma unroll
                for (int e = 0; e < 2; ++e) {
                    const int q = (ks << 1) + e;
                    const float Icur = Inx;
                    if (q + 1 < TW) Inx = Il[(q + 1) * 256 + tid];
                    const int t = tb + q;
                    const size_t pbase = (size_t)t * STP_ + boff;

                    // canonical explicit-fma form (pinned, R14 verbatim):
                    const float m1 = v2_ * v;
                    const float t2 = v1_ * v;
                    const float P  = __builtin_fmaf(m1, v, t2);
                    const float Q  = (P + v0_) - u;
                    const float vm = v + (Q + Icur);
                    const float tb2 = __builtin_fmaf(b_, v, -u);
                    const float um = __builtin_fmaf(coef, tb2, u);

                    const bool  sp = (vm - th_) > 0.f;
                    v = sp ? c_ : vm;        // == vm*(1-s)+s*c exactly
                    u = sp ? (um + d_) : um; // == um + s*d

                    states[pbase]           = v;
                    states[pbase + BN_]     = u;

                    const unsigned long long mset = __ballot(sp);
                    if (lane == 0) dotm[t][w] = mset;
                }
            }
            if (ks < 31) {               // write next W slice after FMAs
                float* Wd = &Ws[(ks + 1) & 1][0];
                Wd[0*256+tid]=q0.x; Wd[1*256+tid]=q0.y; Wd[2*256+tid]=q0.z; Wd[3*256+tid]=q0.w;
                Wd[4*256+tid]=q1.x; Wd[5*256+tid]=q1.y; Wd[6*256+tid]=q1.z; Wd[7*256+tid]=q1.w;
            }
            SOFT_BAR();
        }

        // chunk end: acc -> Il (scan of cc-1 fully consumed Il; barrier above)
#pragma unroll
        for (int i = 0; i < 8; ++i) {
            const int t = tg + i;
            *(float4*)&Il[t * 256 + h4] =
                make_float4(acc[i][0], acc[i][1], acc[i][2], acc[i][3]);
            *(float4*)&Il[t * 256 + h4 + 128] =
                make_float4(acc[i][4], acc[i][5], acc[i][6], acc[i][7]);
        }
        if (cc + 1 < NCHUNK) {           // next chunk's X (regs, issued ks=24)
#pragma unroll
            for (int r = 0; r < 16; ++r) {
                const int k = r * 16 + wq;
                Xl[(k + 0) * 64 + tl] = ra[r].x;
                Xl[(k + 1) * 64 + tl] = ra[r].y;
                Xl[(k + 2) * 64 + tl] = ra[r].z;
                Xl[(k + 3) * 64 + tl] = ra[r].w;
            }
            float* Wd = &Ws[0][0];       // restage W slice 0 from held regs
            Wd[0*256+tid]=z0.x; Wd[1*256+tid]=z0.y; Wd[2*256+tid]=z0.z; Wd[3*256+tid]=z0.w;
            Wd[4*256+tid]=z1.x; Wd[5*256+tid]=z1.y; Wd[6*256+tid]=z1.z; Wd[7*256+tid]=z1.w;
        }
        SOFT_BAR();
        Inx = Il[tid];                   // prefetch first I of chunk cc's scan
    }

    // epilogue: scan chunk 7 (52 steps), not overlapped (v,u stores only)
    {
        const int tbE = 7 * TW;          // 448
        for (int q = 0; q < 52; ++q) {
            const float Icur = Inx;
            if (q + 1 < 52) Inx = Il[(q + 1) * 256 + tid];
            const int t = tbE + q;
            const size_t pbase = (size_t)t * STP_ + boff;

            const float m1 = v2_ * v;
            const float t2 = v1_ * v;
            const float P  = __builtin_fmaf(m1, v, t2);
            const float Q  = (P + v0_) - u;
            const float vm = v + (Q + Icur);
            const float tb2 = __builtin_fmaf(b_, v, -u);
            const float um = __builtin_fmaf(coef, tb2, u);

            const bool  sp = (vm - th_) > 0.f;
            v = sp ? c_ : vm;
            u = sp ? (um + d_) : um;

            states[pbase]           = v;
            states[pbase + BN_]     = u;

            const unsigned long long mset = __ballot(sp);
            if (lane == 0) dotm[t][w] = mset;
        }
    }
    __syncthreads();                     // dotm complete

    // ---------------- s materialization from masks (streaming) ----------
    // s == own bit of the wave's ballot mask: bit-identical to the in-loop
    // value. Independent iterations -> deep pipelining, write-BW-bound.
    {
        float* sbase = states + 2 * BN_ + boff;
        float* obase = out_s + boff;
        for (int t = 0; t < T_; ++t) {
            const unsigned long long m = dotm[t][w];   // broadcast LDS read
            const float s = (float)((m >> lane) & 1ull);
            sbase[(size_t)t * STP_] = s;
            obase[(size_t)t * BN_]  = s;
        }
    }

    // masks -> dots (w2l/dotf overlay on dead Ws region: 256+2000 <= 4096 floats)
    float* scr  = &Ws[0][0];
    float* w2l  = scr;                   // [256]
    float* dotf = scr + 256;             // [500][4]
    w2l[tid] = W2[tid];
    __syncthreads();
    for (int p = tid; p < T_ * 4; p += 256) {
        const int t  = p >> 2;
        const int ww = p & 3;
        unsigned long long m = dotm[t][ww];
        const float* wl = &w2l[ww << 6];
        float sum = 0.f;
        while (m) {
            const int i = __builtin_ctzll(m);
            sum += wl[i];
            m &= (m - 1);
        }
        dotf[t * 4 + ww] = sum;
    }
    __syncthreads();

    if (tid == 0) {
        const float lk_  = pleak[0];
        const float olk_ = 1.0f - lk_;
        float li = st_li[bb];
        for (int t = 0; t < T_; ++t) {
            const float dot = (dotf[t*4+0] + dotf[t*4+1]) + (dotf[t*4+2] + dotf[t*4+3]);
            li = lk_ * li + olk_ * dot;
            out_dec[(size_t)t * 256 + bb] = li;
        }
    }
}

// ---------------------------------------------------------------------------
extern "C" void kernel_launch(void* const* d_in, const int* in_sizes, int n_in,
                              void* d_out, int out_size, void* d_ws, size_t ws_size,
                              hipStream_t stream) {
    const float* input  = (const float*)d_in[0];   // [B,T,N]
    const float* st_snn = (const float*)d_in[1];   // [3,B,N]
    const float* st_li  = (const float*)d_in[2];   // [B,1]
    const float* W1     = (const float*)d_in[3];   // [N,N]
    const float* W2     = (const float*)d_in[4];   // [1,N]
    const float* pa     = (const float*)d_in[5];
    const float* pb     = (const float*)d_in[6];
    const float* pc     = (const float*)d_in[7];
    const float* pd     = (const float*)d_in[8];
    const float* pv0    = (const float*)d_in[9];
    const float* pv1    = (const float*)d_in[10];
    const float* pv2    = (const float*)d_in[11];
    const float* ptau   = (const float*)d_in[12];
    const float* pth    = (const float*)d_in[13];
    const float* pleak  = (const float*)d_in[14];

    float* out        = (float*)d_out;
    float* out_s      = out;                                        // [500,256,256]
    float* out_states = out + (size_t)T_ * BN_;                     // [500,3,256,256]
    float* out_dec    = out + (size_t)T_ * BN_ + (size_t)T_ * STP_; // [500,256]

    fused_snn_kernel<<<dim3(B_), dim3(256), 0, stream>>>(
        input, W1, out_s, out_states, out_dec, st_snn, st_li, W2,
        pa, pb, pc, pd, pv0, pv1, pv2, ptau, pth, pleak);
}

// Round 20
// 362.622 us; speedup vs baseline: 1.1282x; 1.0736x over previous
//
#include <hip/hip_runtime.h>

#define B_ 256
#define T_ 500
#define N_ 256
#define BN_ 65536            // B_*N_
#define STP_ 196608          // 3*B_*N_ (states per-t stride)
#define TW 64                // t-window per chunk
#define NCHUNK 8             // ceil(500/64)

// Soft barrier: LDS-visibility sync without vmcnt(0) store drain (stores have
// no in-kernel consumer). sched_barrier fences per rule #18.
#define SOFT_BAR() do {                                   \
    __builtin_amdgcn_sched_barrier(0);                    \
    asm volatile("s_waitcnt lgkmcnt(0)" ::: "memory");    \
    __builtin_amdgcn_s_barrier();                         \
    __builtin_amdgcn_sched_barrier(0);                    \
} while (0)

// ---------------------------------------------------------------------------
// Fused GEMM + Izhikevich scan, chunk-PIPELINED. One block per batch b.
// == R17 exactly (best measured: 362 us, absmax 1.2207e-4) ==
// R18 (permlane B-read) and R19 (s-store end-pass) both regressed; reverted.
// Structure: LDS Xl (X chunk c, [k][t]) + Il (I chunk c-1, [t][n]) + Ws
// (BK=8 dbuf) + dotm = 163.84 KB (full LDS pool, 1 block/CU). Per ks-slice
// of chunk c's GEMM (8x8 microtile, k-ascending), 2 scan steps of chunk c-1
// run interleaved so the 4 stores/step drain under FMA/LDS work. Scan text
// is the R14-PINNED explicit-__builtin_fmaf form (context-immune: held
// bit-identical through 5 restructures). li from ballot masks at the end.
// ---------------------------------------------------------------------------
__global__ __launch_bounds__(256)
void fused_snn_kernel(const float* __restrict__ X, const float* __restrict__ W1,
                      float* __restrict__ out_s, float* __restrict__ states,
                      float* __restrict__ out_dec,
                      const float* __restrict__ st_snn, const float* __restrict__ st_li,
                      const float* __restrict__ W2,
                      const float* __restrict__ pa, const float* __restrict__ pb,
                      const float* __restrict__ pc, const float* __restrict__ pd,
                      const float* __restrict__ pv0, const float* __restrict__ pv1,
                      const float* __restrict__ pv2, const float* __restrict__ ptau,
                      const float* __restrict__ pth, const float* __restrict__ pleak) {
    __shared__ float Xl[TW * 256];              // 64 KB: X chunk c, [k][t]
    __shared__ float Il[TW * 256];              // 64 KB: I chunk c-1, [t][n]
    __shared__ float Ws[2][8 * 256];            // 16 KB: W1t BK=8 slice dbuf
    __shared__ unsigned long long dotm[T_][4];  // 16000 B: per-wave spike masks

    const int bb   = blockIdx.x;
    const int tid  = threadIdx.x;
    const int w    = tid >> 6;
    const int lane = tid & 63;
    const int boff = bb * 256 + tid;

    // scan per-thread state & params
    float v = st_snn[boff];
    float u = st_snn[BN_ + boff];
    const float a_   = pa[tid];
    const float b_   = pb[tid];
    const float c_   = pc[tid];
    const float d_   = pd[tid];
    const float v0_  = pv0[tid];
    const float v1_  = pv1[tid];
    const float v2_  = pv2[tid];
    const float coef = (1.0f / ptau[tid]) * a_;  // (DT/tau_u)*a, DT=1
    const float th_  = pth[tid];

    // GEMM microtile: 8 t-groups x 32 n-groups, 8x8 per thread
    const int g   = tid >> 5;            // t rows 8g..8g+7
    const int tg  = g << 3;
    const int h4  = (tid & 31) << 2;     // n cols h4..h4+3 and h4+128..h4+131

    const float* Xb = X + (size_t)bb * (T_ * 256);
    const int tl = tid & 63;             // X-stage t_loc
    const int wq = (tid >> 6) << 2;      // X-stage k sub-quad

    // W slice 0 (k 0..7) held permanently in regs (chunk-invariant)
    const float* Wr0 = W1 + (size_t)tid * 256;
    const float4 z0 = *(const float4*)(Wr0 + 0);
    const float4 z1 = *(const float4*)(Wr0 + 4);

    // stage X chunk 0 (valid=64) and W slice 0
    float4 ra[16];
    {
        const float* Xrow = Xb + (size_t)tl * 256;
#pragma unroll
        for (int r = 0; r < 16; ++r)
            ra[r] = *(const float4*)(Xrow + r * 16 + wq);
    }
#pragma unroll
    for (int r = 0; r < 16; ++r) {
        const int k = r * 16 + wq;
        Xl[(k + 0) * 64 + tl] = ra[r].x;
        Xl[(k + 1) * 64 + tl] = ra[r].y;
        Xl[(k + 2) * 64 + tl] = ra[r].z;
        Xl[(k + 3) * 64 + tl] = ra[r].w;
    }
    {
        float* Wd = &Ws[0][0];
        Wd[0*256+tid]=z0.x; Wd[1*256+tid]=z0.y; Wd[2*256+tid]=z0.z; Wd[3*256+tid]=z0.w;
        Wd[4*256+tid]=z1.x; Wd[5*256+tid]=z1.y; Wd[6*256+tid]=z1.z; Wd[7*256+tid]=z1.w;
    }
    SOFT_BAR();

    float Inx = 0.f;                     // scan I-prefetch register

    for (int cc = 0; cc < NCHUNK; ++cc) {
        const int tb = (cc - 1) * TW;    // scan chunk base (used when cc>0)

        float acc[8][8];
#pragma unroll
        for (int i = 0; i < 8; ++i)
#pragma unroll
            for (int j = 0; j < 8; ++j) acc[i][j] = 0.f;

        for (int ks = 0; ks < 32; ++ks) {
            float4 q0, q1;
            if (ks < 31) {               // next W slice (k 8(ks+1)..+8) from L2
                const float* Wr = W1 + (size_t)tid * 256 + (ks + 1) * 8;
                q0 = *(const float4*)(Wr);
                q1 = *(const float4*)(Wr + 4);
            }
            if (ks == 24 && cc + 1 < NCHUNK) {   // issue next-chunk X loads
                const int t0n    = (cc + 1) * TW;
                const int validn = (T_ - t0n < TW) ? (T_ - t0n) : TW;
                const int tsrc   = t0n + ((tl < validn) ? tl : (validn - 1));
                const float* Xrow = Xb + (size_t)tsrc * 256;
#pragma unroll
                for (int r = 0; r < 16; ++r)
                    ra[r] = *(const float4*)(Xrow + r * 16 + wq);
            }
            const float* Wc = &Ws[ks & 1][0];
            const int kbase = ks << 3;
#pragma unroll
            for (int kk = 0; kk < 8; ++kk) {
                const float4 a0 = *(const float4*)&Xl[(kbase + kk) * 64 + tg];
                const float4 a1 = *(const float4*)&Xl[(kbase + kk) * 64 + tg + 4];
                const float4 b0 = *(const float4*)&Wc[kk * 256 + h4];
                const float4 b1 = *(const float4*)&Wc[kk * 256 + h4 + 128];
                const float avr[8] = {a0.x, a0.y, a0.z, a0.w, a1.x, a1.y, a1.z, a1.w};
                const float bvr[8] = {b0.x, b0.y, b0.z, b0.w, b1.x, b1.y, b1.z, b1.w};
#pragma unroll
                for (int i = 0; i < 8; ++i)
#pragma unroll
                    for (int j = 0; j < 8; ++j)
                        acc[i][j] += avr[i] * bvr[j];
            }
            // interleaved scan: 2 steps of chunk cc-1 (stores drain under GEMM)
            if (cc > 0) {
#pragma unroll
                for (int e = 0; e < 2; ++e) {
                    const int q = (ks << 1) + e;
                    const float Icur = Inx;
                    if (q + 1 < TW) Inx = Il[(q + 1) * 256 + tid];
                    const int t = tb + q;
                    const size_t pbase = (size_t)t * STP_ + boff;

                    // canonical explicit-fma form (pinned, R14 verbatim):
                    const float m1 = v2_ * v;
                    const float t2 = v1_ * v;
                    const float P  = __builtin_fmaf(m1, v, t2);
                    const float Q  = (P + v0_) - u;
                    const float vm = v + (Q + Icur);
                    const float tb2 = __builtin_fmaf(b_, v, -u);
                    const float um = __builtin_fmaf(coef, tb2, u);

                    const bool  sp = (vm - th_) > 0.f;
                    const float s  = sp ? 1.f : 0.f;
                    v = sp ? c_ : vm;        // == vm*(1-s)+s*c exactly
                    u = sp ? (um + d_) : um; // == um + s*d

                    states[pbase]           = v;
                    states[pbase + BN_]     = u;
                    states[pbase + 2 * BN_] = s;
                    out_s[(size_t)t * BN_ + boff] = s;

                    const unsigned long long mset = __ballot(sp);
                    if (lane == 0) dotm[t][w] = mset;
                }
            }
            if (ks < 31) {               // write next W slice after FMAs
                float* Wd = &Ws[(ks + 1) & 1][0];
                Wd[0*256+tid]=q0.x; Wd[1*256+tid]=q0.y; Wd[2*256+tid]=q0.z; Wd[3*256+tid]=q0.w;
                Wd[4*256+tid]=q1.x; Wd[5*256+tid]=q1.y; Wd[6*256+tid]=q1.z; Wd[7*256+tid]=q1.w;
            }
            SOFT_BAR();
        }

        // chunk end: acc -> Il (scan of cc-1 fully consumed Il; barrier above)
#pragma unroll
        for (int i = 0; i < 8; ++i) {
            const int t = tg + i;
            *(float4*)&Il[t * 256 + h4] =
                make_float4(acc[i][0], acc[i][1], acc[i][2], acc[i][3]);
            *(float4*)&Il[t * 256 + h4 + 128] =
                make_float4(acc[i][4], acc[i][5], acc[i][6], acc[i][7]);
        }
        if (cc + 1 < NCHUNK) {           // next chunk's X (regs, issued ks=24)
#pragma unroll
            for (int r = 0; r < 16; ++r) {
                const int k = r * 16 + wq;
                Xl[(k + 0) * 64 + tl] = ra[r].x;
                Xl[(k + 1) * 64 + tl] = ra[r].y;
                Xl[(k + 2) * 64 + tl] = ra[r].z;
                Xl[(k + 3) * 64 + tl] = ra[r].w;
            }
            float* Wd = &Ws[0][0];       // restage W slice 0 from held regs
            Wd[0*256+tid]=z0.x; Wd[1*256+tid]=z0.y; Wd[2*256+tid]=z0.z; Wd[3*256+tid]=z0.w;
            Wd[4*256+tid]=z1.x; Wd[5*256+tid]=z1.y; Wd[6*256+tid]=z1.z; Wd[7*256+tid]=z1.w;
        }
        SOFT_BAR();
        Inx = Il[tid];                   // prefetch first I of chunk cc's scan
    }

    // epilogue: scan chunk 7 (52 steps), not overlapped
    {
        const int tbE = 7 * TW;          // 448
        for (int q = 0; q < 52; ++q) {
            const float Icur = Inx;
            if (q + 1 < 52) Inx = Il[(q + 1) * 256 + tid];
            const int t = tbE + q;
            const size_t pbase = (size_t)t * STP_ + boff;

            const float m1 = v2_ * v;
            const float t2 = v1_ * v;
            const float P  = __builtin_fmaf(m1, v, t2);
            const float Q  = (P + v0_) - u;
            const float vm = v + (Q + Icur);
            const float tb2 = __builtin_fmaf(b_, v, -u);
            const float um = __builtin_fmaf(coef, tb2, u);

            const bool  sp = (vm - th_) > 0.f;
            const float s  = sp ? 1.f : 0.f;
            v = sp ? c_ : vm;
            u = sp ? (um + d_) : um;

            states[pbase]           = v;
            states[pbase + BN_]     = u;
            states[pbase + 2 * BN_] = s;
            out_s[(size_t)t * BN_ + boff] = s;

            const unsigned long long mset = __ballot(sp);
            if (lane == 0) dotm[t][w] = mset;
        }
    }
    __syncthreads();                     // dotm complete

    // masks -> dots (w2l/dotf overlay on dead Ws region: 256+2000 <= 4096 floats)
    float* scr  = &Ws[0][0];
    float* w2l  = scr;                   // [256]
    float* dotf = scr + 256;             // [500][4]
    w2l[tid] = W2[tid];
    __syncthreads();
    for (int p = tid; p < T_ * 4; p += 256) {
        const int t  = p >> 2;
        const int ww = p & 3;
        unsigned long long m = dotm[t][ww];
        const float* wl = &w2l[ww << 6];
        float sum = 0.f;
        while (m) {
            const int i = __builtin_ctzll(m);
            sum += wl[i];
            m &= (m - 1);
        }
        dotf[t * 4 + ww] = sum;
    }
    __syncthreads();

    if (tid == 0) {
        const float lk_  = pleak[0];
        const float olk_ = 1.0f - lk_;
        float li = st_li[bb];
        for (int t = 0; t < T_; ++t) {
            const float dot = (dotf[t*4+0] + dotf[t*4+1]) + (dotf[t*4+2] + dotf[t*4+3]);
            li = lk_ * li + olk_ * dot;
            out_dec[(size_t)t * 256 + bb] = li;
        }
    }
}

// ---------------------------------------------------------------------------
extern "C" void kernel_launch(void* const* d_in, const int* in_sizes, int n_in,
                              void* d_out, int out_size, void* d_ws, size_t ws_size,
                              hipStream_t stream) {
    const float* input  = (const float*)d_in[0];   // [B,T,N]
    const float* st_snn = (const float*)d_in[1];   // [3,B,N]
    const float* st_li  = (const float*)d_in[2];   // [B,1]
    const float* W1     = (const float*)d_in[3];   // [N,N]
    const float* W2     = (const float*)d_in[4];   // [1,N]
    const float* pa     = (const float*)d_in[5];
    const float* pb     = (const float*)d_in[6];
    const float* pc     = (const float*)d_in[7];
    const float* pd     = (const float*)d_in[8];
    const float* pv0    = (const float*)d_in[9];
    const float* pv1    = (const float*)d_in[10];
    const float* pv2    = (const float*)d_in[11];
    const float* ptau   = (const float*)d_in[12];
    const float* pth    = (const float*)d_in[13];
    const float* pleak  = (const float*)d_in[14];

    float* out        = (float*)d_out;
    float* out_s      = out;                                        // [500,256,256]
    float* out_states = out + (size_t)T_ * BN_;                     // [500,3,256,256]
    float* out_dec    = out + (size_t)T_ * BN_ + (size_t)T_ * STP_; // [500,256]

    fused_snn_kernel<<<dim3(B_), dim3(256), 0, stream>>>(
        input, W1, out_s, out_states, out_dec, st_snn, st_li, W2,
        pa, pb, pc, pd, pv0, pv1, pv2, ptau, pth, pleak);
}

// Round 21
// 338.892 us; speedup vs baseline: 1.2072x; 1.0700x over previous
//
#include <hip/hip_runtime.h>

#define B_ 256
#define T_ 500
#define N_ 256
#define BN_ 65536            // B_*N_
#define STP_ 196608          // 3*B_*N_ (states per-t stride)
#define TW 64                // t-window per chunk
#define NCHUNK 8             // ceil(500/64)
#define NTHR 512

// Soft barrier: LDS-visibility sync without vmcnt(0) store drain (stores have
// no in-kernel consumer). sched_barrier fences per rule #18.
#define SOFT_BAR() do {                                   \
    __builtin_amdgcn_sched_barrier(0);                    \
    asm volatile("s_waitcnt lgkmcnt(0)" ::: "memory");    \
    __builtin_amdgcn_s_barrier();                         \
    __builtin_amdgcn_sched_barrier(0);                    \
} while (0)

// ---------------------------------------------------------------------------
// Fused GEMM + Izhikevich scan, chunk-PIPELINED, 512 threads (2 waves/SIMD).
// R17 structure; per-thread register footprint redesigned to fit the 128-VGPR
// cap that killed R6/R7: ra[8] (not 16), 1-float4 W stage/prefetch per
// thread, acc[4][8] microtile (~110 VGPR total -> no spill at cap 128).
// GEMM: 16 t-groups x 32 n-groups, per kk 1 broadcast A-b128 + 2 B-b128 +
// 32 FMAs; k-chain per output ascending 0..255 == R17 -> bit-identical I.
// Scan: tid<256, R14-PINNED fmaf text (context-immune, proven R14-R17),
// 2 steps interleaved per ks as in R17. li from ballot masks at the end.
// ---------------------------------------------------------------------------
__global__ __launch_bounds__(NTHR)
void fused_snn_kernel(const float* __restrict__ X, const float* __restrict__ W1,
                      float* __restrict__ out_s, float* __restrict__ states,
                      float* __restrict__ out_dec,
                      const float* __restrict__ st_snn, const float* __restrict__ st_li,
                      const float* __restrict__ W2,
                      const float* __restrict__ pa, const float* __restrict__ pb,
                      const float* __restrict__ pc, const float* __restrict__ pd,
                      const float* __restrict__ pv0, const float* __restrict__ pv1,
                      const float* __restrict__ pv2, const float* __restrict__ ptau,
                      const float* __restrict__ pth, const float* __restrict__ pleak) {
    __shared__ float Xl[TW * 256];              // 64 KB: X chunk c, [k][t]
    __shared__ float Il[TW * 256];              // 64 KB: I chunk c-1, [t][n]
    __shared__ float Ws[2][8 * 256];            // 16 KB: W1t BK=8 slice dbuf
    __shared__ unsigned long long dotm[T_][4];  // 16000 B: per-wave spike masks

    const int bb   = blockIdx.x;
    const int tid  = threadIdx.x;
    const int w    = tid >> 6;           // wave (0..7); scan uses 0..3
    const int lane = tid & 63;
    const int pn   = tid & 255;
    const int boff = bb * 256 + pn;

    // scan per-thread state & params (used by tid<256 only)
    float v = st_snn[boff];
    float u = st_snn[BN_ + boff];
    const float b_   = pb[pn];
    const float c_   = pc[pn];
    const float d_   = pd[pn];
    const float v0_  = pv0[pn];
    const float v1_  = pv1[pn];
    const float v2_  = pv2[pn];
    const float coef = (1.0f / ptau[pn]) * pa[pn];   // (DT/tau_u)*a, DT=1
    const float th_  = pth[pn];

    // GEMM microtile: 16 t-groups x 32 n-groups, 4x8 per thread
    const int tg4 = (tid >> 5) << 2;     // t rows tg4..tg4+3
    const int h4  = (tid & 31) << 2;     // n cols h4..h4+3 and h4+128..h4+131

    const float* Xb = X + (size_t)bb * (T_ * 256);
    const int tl = tid & 63;             // X-stage t_loc
    const int wq = (tid >> 6) << 2;      // X-stage k sub-quad (k = wq + 32r)

    // W-stage map: thread covers row wn, k sub-quad wk of each slice
    const int wn = tid >> 1;             // 0..255
    const int wk = (tid & 1) << 2;       // 0 or 4

    // W slice 0 (k wk..wk+3 of row wn) held permanently in regs
    const float4 z0 = *(const float4*)(W1 + (size_t)wn * 256 + wk);

    // stage X chunk 0 (valid=64) and W slice 0
    float4 ra[8];
    {
        const float* Xrow = Xb + (size_t)tl * 256;
#pragma unroll
        for (int r = 0; r < 8; ++r)
            ra[r] = *(const float4*)(Xrow + wq + (r << 5));
    }
#pragma unroll
    for (int r = 0; r < 8; ++r) {
        const int k = wq + (r << 5);
        Xl[(k + 0) * 64 + tl] = ra[r].x;
        Xl[(k + 1) * 64 + tl] = ra[r].y;
        Xl[(k + 2) * 64 + tl] = ra[r].z;
        Xl[(k + 3) * 64 + tl] = ra[r].w;
    }
    {
        float* Wd = &Ws[0][0];
        Wd[(wk + 0) * 256 + wn] = z0.x;
        Wd[(wk + 1) * 256 + wn] = z0.y;
        Wd[(wk + 2) * 256 + wn] = z0.z;
        Wd[(wk + 3) * 256 + wn] = z0.w;
    }
    SOFT_BAR();

    float Inx = 0.f;                     // scan I-prefetch register

    for (int cc = 0; cc < NCHUNK; ++cc) {
        const int tb = (cc - 1) * TW;    // scan chunk base (used when cc>0)

        float acc[4][8];
#pragma unroll
        for (int i = 0; i < 4; ++i)
#pragma unroll
            for (int j = 0; j < 8; ++j) acc[i][j] = 0.f;

        for (int ks = 0; ks < 32; ++ks) {
            float4 q0;
            if (ks < 31) {               // next W slice quad from L2
                q0 = *(const float4*)(W1 + (size_t)wn * 256 + (ks + 1) * 8 + wk);
            }
            if (ks == 24 && cc + 1 < NCHUNK) {   // issue next-chunk X loads
                const int t0n    = (cc + 1) * TW;
                const int validn = (T_ - t0n < TW) ? (T_ - t0n) : TW;
                const int tsrc   = t0n + ((tl < validn) ? tl : (validn - 1));
                const float* Xrow = Xb + (size_t)tsrc * 256;
#pragma unroll
                for (int r = 0; r < 8; ++r)
                    ra[r] = *(const float4*)(Xrow + wq + (r << 5));
            }
            const float* Wc = &Ws[ks & 1][0];
            const int kbase = ks << 3;
#pragma unroll
            for (int kk = 0; kk < 8; ++kk) {
                const float4 a0 = *(const float4*)&Xl[(kbase + kk) * 64 + tg4];
                const float4 b0 = *(const float4*)&Wc[kk * 256 + h4];
                const float4 b1 = *(const float4*)&Wc[kk * 256 + h4 + 128];
                const float avr[4] = {a0.x, a0.y, a0.z, a0.w};
                const float bvr[8] = {b0.x, b0.y, b0.z, b0.w, b1.x, b1.y, b1.z, b1.w};
#pragma unroll
                for (int i = 0; i < 4; ++i)
#pragma unroll
                    for (int j = 0; j < 8; ++j)
                        acc[i][j] += avr[i] * bvr[j];
            }
            // interleaved scan: 2 steps of chunk cc-1 (waves 0-3 only)
            if (cc > 0 && tid < 256) {
#pragma unroll
                for (int e = 0; e < 2; ++e) {
                    const int q = (ks << 1) + e;
                    const float Icur = Inx;
                    if (q + 1 < TW) Inx = Il[(q + 1) * 256 + pn];
                    const int t = tb + q;
                    const size_t pbase = (size_t)t * STP_ + boff;

                    // canonical explicit-fma form (pinned, R14 verbatim):
                    const float m1 = v2_ * v;
                    const float t2 = v1_ * v;
                    const float P  = __builtin_fmaf(m1, v, t2);
                    const float Q  = (P + v0_) - u;
                    const float vm = v + (Q + Icur);
                    const float tb2 = __builtin_fmaf(b_, v, -u);
                    const float um = __builtin_fmaf(coef, tb2, u);

                    const bool  sp = (vm - th_) > 0.f;
                    const float s  = sp ? 1.f : 0.f;
                    v = sp ? c_ : vm;        // == vm*(1-s)+s*c exactly
                    u = sp ? (um + d_) : um; // == um + s*d

                    states[pbase]           = v;
                    states[pbase + BN_]     = u;
                    states[pbase + 2 * BN_] = s;
                    out_s[(size_t)t * BN_ + boff] = s;

                    const unsigned long long mset = __ballot(sp);
                    if (lane == 0) dotm[t][w] = mset;
                }
            }
            if (ks < 31) {               // write next W slice after FMAs
                float* Wd = &Ws[(ks + 1) & 1][0];
                Wd[(wk + 0) * 256 + wn] = q0.x;
                Wd[(wk + 1) * 256 + wn] = q0.y;
                Wd[(wk + 2) * 256 + wn] = q0.z;
                Wd[(wk + 3) * 256 + wn] = q0.w;
            }
            SOFT_BAR();
        }

        // chunk end: acc -> Il (scan of cc-1 fully consumed Il; barrier above)
#pragma unroll
        for (int i = 0; i < 4; ++i) {
            const int t = tg4 + i;
            *(float4*)&Il[t * 256 + h4] =
                make_float4(acc[i][0], acc[i][1], acc[i][2], acc[i][3]);
            *(float4*)&Il[t * 256 + h4 + 128] =
                make_float4(acc[i][4], acc[i][5], acc[i][6], acc[i][7]);
        }
        if (cc + 1 < NCHUNK) {           // next chunk's X (regs, issued ks=24)
#pragma unroll
            for (int r = 0; r < 8; ++r) {
                const int k = wq + (r << 5);
                Xl[(k + 0) * 64 + tl] = ra[r].x;
                Xl[(k + 1) * 64 + tl] = ra[r].y;
                Xl[(k + 2) * 64 + tl] = ra[r].z;
                Xl[(k + 3) * 64 + tl] = ra[r].w;
            }
            float* Wd = &Ws[0][0];       // restage W slice 0 from held regs
            Wd[(wk + 0) * 256 + wn] = z0.x;
            Wd[(wk + 1) * 256 + wn] = z0.y;
            Wd[(wk + 2) * 256 + wn] = z0.z;
            Wd[(wk + 3) * 256 + wn] = z0.w;
        }
        SOFT_BAR();
        Inx = Il[pn];                    // prefetch first I of chunk cc's scan
    }

    // epilogue: scan chunk 7 (52 steps), not overlapped (waves 0-3)
    if (tid < 256) {
        const int tbE = 7 * TW;          // 448
        for (int q = 0; q < 52; ++q) {
            const float Icur = Inx;
            if (q + 1 < 52) Inx = Il[(q + 1) * 256 + pn];
            const int t = tbE + q;
            const size_t pbase = (size_t)t * STP_ + boff;

            const float m1 = v2_ * v;
            const float t2 = v1_ * v;
            const float P  = __builtin_fmaf(m1, v, t2);
            const float Q  = (P + v0_) - u;
            const float vm = v + (Q + Icur);
            const float tb2 = __builtin_fmaf(b_, v, -u);
            const float um = __builtin_fmaf(coef, tb2, u);

            const bool  sp = (vm - th_) > 0.f;
            const float s  = sp ? 1.f : 0.f;
            v = sp ? c_ : vm;
            u = sp ? (um + d_) : um;

            states[pbase]           = v;
            states[pbase + BN_]     = u;
            states[pbase + 2 * BN_] = s;
            out_s[(size_t)t * BN_ + boff] = s;

            const unsigned long long mset = __ballot(sp);
            if (lane == 0) dotm[t][w] = mset;
        }
    }
    __syncthreads();                     // dotm complete

    // masks -> dots (w2l/dotf overlay on dead Ws region: 256+2000 <= 4096 floats)
    float* scr  = &Ws[0][0];
    float* w2l  = scr;                   // [256]
    float* dotf = scr + 256;             // [500][4]
    if (tid < 256) w2l[tid] = W2[tid];
    __syncthreads();
    for (int p = tid; p < T_ * 4; p += NTHR) {
        const int t  = p >> 2;
        const int ww = p & 3;
        unsigned long long m = dotm[t][ww];
        const float* wl = &w2l[ww << 6];
        float sum = 0.f;
        while (m) {
            const int i = __builtin_ctzll(m);
            sum += wl[i];
            m &= (m - 1);
        }
        dotf[t * 4 + ww] = sum;
    }
    __syncthreads();

    if (tid == 0) {
        const float lk_  = pleak[0];
        const float olk_ = 1.0f - lk_;
        float li = st_li[bb];
        for (int t = 0; t < T_; ++t) {
            const float dot = (dotf[t*4+0] + dotf[t*4+1]) + (dotf[t*4+2] + dotf[t*4+3]);
            li = lk_ * li + olk_ * dot;
            out_dec[(size_t)t * 256 + bb] = li;
        }
    }
}

// ---------------------------------------------------------------------------
extern "C" void kernel_launch(void* const* d_in, const int* in_sizes, int n_in,
                              void* d_out, int out_size, void* d_ws, size_t ws_size,
                              hipStream_t stream) {
    const float* input  = (const float*)d_in[0];   // [B,T,N]
    const float* st_snn = (const float*)d_in[1];   // [3,B,N]
    const float* st_li  = (const float*)d_in[2];   // [B,1]
    const float* W1     = (const float*)d_in[3];   // [N,N]
    const float* W2     = (const float*)d_in[4];   // [1,N]
    const float* pa     = (const float*)d_in[5];
    const float* pb     = (const float*)d_in[6];
    const float* pc     = (const float*)d_in[7];
    const float* pd     = (const float*)d_in[8];
    const float* pv0    = (const float*)d_in[9];
    const float* pv1    = (const float*)d_in[10];
    const float* pv2    = (const float*)d_in[11];
    const float* ptau   = (const float*)d_in[12];
    const float* pth    = (const float*)d_in[13];
    const float* pleak  = (const float*)d_in[14];

    float* out        = (float*)d_out;
    float* out_s      = out;                                        // [500,256,256]
    float* out_states = out + (size_t)T_ * BN_;                     // [500,3,256,256]
    float* out_dec    = out + (size_t)T_ * BN_ + (size_t)T_ * STP_; // [500,256]

    fused_snn_kernel<<<dim3(B_), dim3(NTHR), 0, stream>>>(
        input, W1, out_s, out_states, out_dec, st_snn, st_li, W2,
        pa, pb, pc, pd, pv0, pv1, pv2, ptau, pth, pleak);
}